// Round 2
// baseline (1421.037 us; speedup 1.0000x reference)
//
#include <hip/hip_runtime.h>

// GCN: h1 = relu(GCNConv(x,W1,b1)); s1 = pool(h1); h2 = relu(GCNConv(h1,W2,b2)); s2 = pool(h2)
// out = [h2 (N*64) | per-graph rows [s1(64) s2(64)] (G*128)]

#define FDIM 64
#define SCAN_CHUNK 1024

__global__ void k_count(const int* __restrict__ dst, int E, int* __restrict__ count) {
    int e = blockIdx.x * blockDim.x + threadIdx.x;
    if (e < E) atomicAdd(&count[dst[e]], 1);
}

__global__ void k_dinv(const int* __restrict__ count, int N, float* __restrict__ dinv) {
    int i = blockIdx.x * blockDim.x + threadIdx.x;
    if (i < N) dinv[i] = rsqrtf((float)count[i] + 1.0f);
}

// ---- 3-phase scan: count[0..N) -> exclusive row_ptr[0..N], row_ptr[N]=E ----
__global__ __launch_bounds__(256) void k_scan1(const int* __restrict__ count, int N,
                                               int* __restrict__ partial) {
    int base = blockIdx.x * SCAN_CHUNK + threadIdx.x * 4;
    int s = 0;
#pragma unroll
    for (int k = 0; k < 4; k++) { int i = base + k; if (i < N) s += count[i]; }
    for (int off = 32; off; off >>= 1) s += __shfl_down(s, off);
    __shared__ int ws[4];
    int lane = threadIdx.x & 63, w = threadIdx.x >> 6;
    if (lane == 0) ws[w] = s;
    __syncthreads();
    if (threadIdx.x == 0) partial[blockIdx.x] = ws[0] + ws[1] + ws[2] + ws[3];
}

__global__ __launch_bounds__(256) void k_scan2(int* __restrict__ partial, int S) {
    int t = threadIdx.x;
    int v = (t < S) ? partial[t] : 0;
    __shared__ int sm[256];
    sm[t] = v; __syncthreads();
    for (int off = 1; off < 256; off <<= 1) {
        int u = (t >= off) ? sm[t - off] : 0;
        __syncthreads();
        sm[t] += u;
        __syncthreads();
    }
    if (t < S) partial[t] = sm[t] - v;   // exclusive
}

__global__ __launch_bounds__(256) void k_scan3(const int* __restrict__ count, int N, int E,
                                               const int* __restrict__ partial,
                                               int* __restrict__ row_ptr) {
    int base = blockIdx.x * SCAN_CHUNK + threadIdx.x * 4;
    int c[4]; int s = 0;
#pragma unroll
    for (int k = 0; k < 4; k++) { int i = base + k; c[k] = (i < N) ? count[i] : 0; s += c[k]; }
    __shared__ int sm[256];
    int t = threadIdx.x;
    sm[t] = s; __syncthreads();
    for (int off = 1; off < 256; off <<= 1) {
        int u = (t >= off) ? sm[t - off] : 0;
        __syncthreads();
        sm[t] += u;
        __syncthreads();
    }
    int run = partial[blockIdx.x] + sm[t] - s;
#pragma unroll
    for (int k = 0; k < 4; k++) { int i = base + k; if (i < N) row_ptr[i] = run; run += c[k]; }
    if (blockIdx.x == 0 && t == 0) row_ptr[N] = E;
}

__global__ void k_scatter(const int* __restrict__ src, const int* __restrict__ dst, int E,
                          const int* __restrict__ row_ptr, int* __restrict__ fill,
                          int* __restrict__ col) {
    int e = blockIdx.x * blockDim.x + threadIdx.x;
    if (e < E) {
        int d = dst[e];
        int pos = row_ptr[d] + atomicAdd(&fill[d], 1);
        col[pos] = src[e];
    }
}

// G[n,:] = dinv[n] * (X[n,:] @ W). 64 rows/block; thread -> 4 rows x float4.
__global__ __launch_bounds__(256) void k_gemm_scale(const float* __restrict__ X,
                                                    const float* __restrict__ W,
                                                    const float* __restrict__ dinv, int N,
                                                    float* __restrict__ G) {
    __shared__ float4 Ws[64 * 16];      // W row-major as float4
    __shared__ float Xs[64][65];        // pad 65: rows 0,4,8,12 hit distinct banks
    int tid = threadIdx.x;
    const float4* W4 = (const float4*)W;
    for (int i = tid; i < 64 * 16; i += 256) Ws[i] = W4[i];
    int rowBase = blockIdx.x * 64;
    // stage 64 rows of X (1024 float4, 4 per thread)
    for (int i = tid; i < 1024; i += 256) {
        int r = i >> 4, f4 = i & 15;
        float4 v = make_float4(0.f, 0.f, 0.f, 0.f);
        if (rowBase + r < N) v = ((const float4*)X)[(size_t)(rowBase + r) * 16 + f4];
        Xs[r][f4 * 4 + 0] = v.x; Xs[r][f4 * 4 + 1] = v.y;
        Xs[r][f4 * 4 + 2] = v.z; Xs[r][f4 * 4 + 3] = v.w;
    }
    __syncthreads();
    int r0 = (tid >> 4) * 4;            // 4 rows per thread
    int c4 = tid & 15;
    float4 acc0 = make_float4(0,0,0,0), acc1 = acc0, acc2 = acc0, acc3 = acc0;
#pragma unroll
    for (int k = 0; k < 64; k++) {
        float4 w = Ws[k * 16 + c4];
        float x0 = Xs[r0 + 0][k], x1 = Xs[r0 + 1][k], x2 = Xs[r0 + 2][k], x3 = Xs[r0 + 3][k];
        acc0.x += x0 * w.x; acc0.y += x0 * w.y; acc0.z += x0 * w.z; acc0.w += x0 * w.w;
        acc1.x += x1 * w.x; acc1.y += x1 * w.y; acc1.z += x1 * w.z; acc1.w += x1 * w.w;
        acc2.x += x2 * w.x; acc2.y += x2 * w.y; acc2.z += x2 * w.z; acc2.w += x2 * w.w;
        acc3.x += x3 * w.x; acc3.y += x3 * w.y; acc3.z += x3 * w.z; acc3.w += x3 * w.w;
    }
    float4* G4 = (float4*)G;
    float4 a[4] = {acc0, acc1, acc2, acc3};
#pragma unroll
    for (int i = 0; i < 4; i++) {
        int row = rowBase + r0 + i;
        if (row < N) {
            float dn = dinv[row];
            float4 v = a[i];
            v.x *= dn; v.y *= dn; v.z *= dn; v.w *= dn;
            G4[(size_t)row * 16 + c4] = v;
        }
    }
}

// 16 lanes per node (float4/lane), 4 nodes/wave, 16 nodes/block.
// col indices loaded cooperatively + shfl-broadcast; gather unrolled x4.
__global__ __launch_bounds__(256) void k_agg(const float4* __restrict__ G4,
                                             const int* __restrict__ row_ptr,
                                             const int* __restrict__ col,
                                             const float* __restrict__ dinv,
                                             const float4* __restrict__ bias4,
                                             const int* __restrict__ batch, int N,
                                             float4* __restrict__ Out4,
                                             float* __restrict__ pool, int poolOff) {
    int tid = threadIdx.x;
    int lane = tid & 63;
    int c4 = tid & 15;
    int laneBase = lane & 48;           // 16-lane group base within wave
    int n = blockIdx.x * 16 + (tid >> 4);
    if (n >= N) return;
    int lo = row_ptr[n], hi = row_ptr[n + 1];
    float4 acc = G4[(size_t)n * 16 + c4];
    for (int e0 = lo; e0 < hi; e0 += 16) {
        int idx = e0 + c4;
        int sv = (idx < hi) ? col[idx] : 0;
        int cnt = hi - e0; if (cnt > 16) cnt = 16;
        int j = 0;
        for (; j + 4 <= cnt; j += 4) {
            int s0 = __shfl(sv, laneBase + j + 0);
            int s1 = __shfl(sv, laneBase + j + 1);
            int s2 = __shfl(sv, laneBase + j + 2);
            int s3 = __shfl(sv, laneBase + j + 3);
            float4 a0 = G4[(size_t)s0 * 16 + c4];
            float4 a1 = G4[(size_t)s1 * 16 + c4];
            float4 a2 = G4[(size_t)s2 * 16 + c4];
            float4 a3 = G4[(size_t)s3 * 16 + c4];
            acc.x += (a0.x + a1.x) + (a2.x + a3.x);
            acc.y += (a0.y + a1.y) + (a2.y + a3.y);
            acc.z += (a0.z + a1.z) + (a2.z + a3.z);
            acc.w += (a0.w + a1.w) + (a2.w + a3.w);
        }
        for (; j < cnt; j++) {
            int s = __shfl(sv, laneBase + j);
            float4 a = G4[(size_t)s * 16 + c4];
            acc.x += a.x; acc.y += a.y; acc.z += a.z; acc.w += a.w;
        }
    }
    float dn = dinv[n];
    float4 b = bias4[c4];
    float4 v;
    v.x = fmaxf(acc.x * dn + b.x, 0.f);
    v.y = fmaxf(acc.y * dn + b.y, 0.f);
    v.z = fmaxf(acc.z * dn + b.z, 0.f);
    v.w = fmaxf(acc.w * dn + b.w, 0.f);
    Out4[(size_t)n * 16 + c4] = v;
    float* pl = &pool[(size_t)batch[n] * 128 + poolOff + c4 * 4];
    atomicAdd(pl + 0, v.x);
    atomicAdd(pl + 1, v.y);
    atomicAdd(pl + 2, v.z);
    atomicAdd(pl + 3, v.w);
}

static inline size_t align256(size_t x) { return (x + 255) & ~(size_t)255; }

extern "C" void kernel_launch(void* const* d_in, const int* in_sizes, int n_in,
                              void* d_out, int out_size, void* d_ws, size_t ws_size,
                              hipStream_t stream) {
    const float* x     = (const float*)d_in[0];
    const int*   ei    = (const int*)d_in[1];
    const int*   batch = (const int*)d_in[2];
    const float* W1    = (const float*)d_in[3];
    const float* b1    = (const float*)d_in[4];
    const float* W2    = (const float*)d_in[5];
    const float* b2    = (const float*)d_in[6];

    const int N = in_sizes[0] / FDIM;
    const int E = in_sizes[1] / 2;
    const int* src = ei;
    const int* dst = ei + E;

    char* p = (char*)d_ws;
    int* count   = (int*)p;   p += align256((size_t)N * 4);
    int* fill    = (int*)p;   p += align256((size_t)N * 4);
    int* row_ptr = (int*)p;   p += align256(((size_t)N + 1) * 4);
    int* col     = (int*)p;   p += align256((size_t)E * 4);
    int* partial = (int*)p;   p += align256(1024 * 4);
    float* dinv  = (float*)p; p += align256((size_t)N * 4);
    float* g     = (float*)p; p += align256((size_t)N * FDIM * 4);
    float* h1    = (float*)p; p += align256((size_t)N * FDIM * 4);

    float* out  = (float*)d_out;
    float* h2   = out;
    float* pool = out + (size_t)N * FDIM;   // [64,128]

    hipMemsetAsync(count, 0, (size_t)N * 4, stream);
    hipMemsetAsync(fill, 0, (size_t)N * 4, stream);
    hipMemsetAsync(pool, 0, (size_t)64 * 128 * 4, stream);

    int eb = (E + 255) / 256;
    int nb = (N + 255) / 256;
    int S  = (N + SCAN_CHUNK - 1) / SCAN_CHUNK;
    int gemmB = (N + 63) / 64;
    int aggB  = (N + 15) / 16;

    k_count<<<eb, 256, 0, stream>>>(dst, E, count);
    k_dinv<<<nb, 256, 0, stream>>>(count, N, dinv);
    k_scan1<<<S, 256, 0, stream>>>(count, N, partial);
    k_scan2<<<1, 256, 0, stream>>>(partial, S);
    k_scan3<<<S, 256, 0, stream>>>(count, N, E, partial, row_ptr);
    k_scatter<<<eb, 256, 0, stream>>>(src, dst, E, row_ptr, fill, col);

    // Layer 1
    k_gemm_scale<<<gemmB, 256, 0, stream>>>(x, W1, dinv, N, g);
    k_agg<<<aggB, 256, 0, stream>>>((const float4*)g, row_ptr, col, dinv,
                                    (const float4*)b1, batch, N, (float4*)h1, pool, 0);

    // Layer 2
    k_gemm_scale<<<gemmB, 256, 0, stream>>>(h1, W2, dinv, N, g);
    k_agg<<<aggB, 256, 0, stream>>>((const float4*)g, row_ptr, col, dinv,
                                    (const float4*)b2, batch, N, (float4*)h2, pool, 64);
}

// Round 4
// 469.491 us; speedup vs baseline: 3.0268x; 3.0268x over previous
//
#include <hip/hip_runtime.h>

// GCN: h1 = relu(GCNConv(x,W1,b1)); s1 = pool(h1); h2 = relu(GCNConv(h1,W2,b2)); s2 = pool(h2)
// out = [h2 (N*64) | per-graph rows [s1(64) s2(64)] (G*128)]
// batch is SORTED -> pooling is contiguous-range segment sum (no atomics).

#define FDIM 64
#define SCAN_CHUNK 1024

__global__ void k_count(const int* __restrict__ dst, int E, int* __restrict__ count) {
    int e = blockIdx.x * blockDim.x + threadIdx.x;
    if (e < E) atomicAdd(&count[dst[e]], 1);
}

__global__ void k_dinv(const int* __restrict__ count, int N, float* __restrict__ dinv) {
    int i = blockIdx.x * blockDim.x + threadIdx.x;
    if (i < N) dinv[i] = rsqrtf((float)count[i] + 1.0f);
}

// ---- 3-phase scan: count[0..N) -> exclusive row_ptr[0..N], row_ptr[N]=E ----
__global__ __launch_bounds__(256) void k_scan1(const int* __restrict__ count, int N,
                                               int* __restrict__ partial) {
    int base = blockIdx.x * SCAN_CHUNK + threadIdx.x * 4;
    int s = 0;
#pragma unroll
    for (int k = 0; k < 4; k++) { int i = base + k; if (i < N) s += count[i]; }
    for (int off = 32; off; off >>= 1) s += __shfl_down(s, off);
    __shared__ int ws[4];
    int lane = threadIdx.x & 63, w = threadIdx.x >> 6;
    if (lane == 0) ws[w] = s;
    __syncthreads();
    if (threadIdx.x == 0) partial[blockIdx.x] = ws[0] + ws[1] + ws[2] + ws[3];
}

__global__ __launch_bounds__(256) void k_scan2(int* __restrict__ partial, int S) {
    int t = threadIdx.x;
    int v = (t < S) ? partial[t] : 0;
    __shared__ int sm[256];
    sm[t] = v; __syncthreads();
    for (int off = 1; off < 256; off <<= 1) {
        int u = (t >= off) ? sm[t - off] : 0;
        __syncthreads();
        sm[t] += u;
        __syncthreads();
    }
    if (t < S) partial[t] = sm[t] - v;   // exclusive
}

__global__ __launch_bounds__(256) void k_scan3(const int* __restrict__ count, int N, int E,
                                               const int* __restrict__ partial,
                                               int* __restrict__ row_ptr) {
    int base = blockIdx.x * SCAN_CHUNK + threadIdx.x * 4;
    int c[4]; int s = 0;
#pragma unroll
    for (int k = 0; k < 4; k++) { int i = base + k; c[k] = (i < N) ? count[i] : 0; s += c[k]; }
    __shared__ int sm[256];
    int t = threadIdx.x;
    sm[t] = s; __syncthreads();
    for (int off = 1; off < 256; off <<= 1) {
        int u = (t >= off) ? sm[t - off] : 0;
        __syncthreads();
        sm[t] += u;
        __syncthreads();
    }
    int run = partial[blockIdx.x] + sm[t] - s;
#pragma unroll
    for (int k = 0; k < 4; k++) { int i = base + k; if (i < N) row_ptr[i] = run; run += c[k]; }
    if (blockIdx.x == 0 && t == 0) row_ptr[N] = E;
}

// Slot allocation via atomicSub on count (count is dead after the scan):
// r = count[d]-- ; pos = row_ptr[d] + r - 1. No separate fill[] buffer.
__global__ void k_scatter(const int* __restrict__ src, const int* __restrict__ dst, int E,
                          const int* __restrict__ row_ptr, int* __restrict__ count,
                          int* __restrict__ col) {
    int e = blockIdx.x * blockDim.x + threadIdx.x;
    if (e < E) {
        int d = dst[e];
        int r = atomicSub(&count[d], 1);
        col[row_ptr[d] + r - 1] = src[e];
    }
}

// Graph boundaries from sorted batch: gstart[g] = first node of graph g; gstart[G]=N.
__global__ void k_bounds(const int* __restrict__ batch, int N, int G, int* __restrict__ gstart) {
    int i = blockIdx.x * blockDim.x + threadIdx.x;
    if (i >= N) return;
    int b = batch[i];
    if (i == 0) { for (int g = 0; g <= b; g++) gstart[g] = 0; }
    else {
        int p = batch[i - 1];
        for (int g = p + 1; g <= b; g++) gstart[g] = i;
    }
    if (i == N - 1) { for (int g = b + 1; g <= G; g++) gstart[g] = N; }
}

// G[n,:] = dinv[n] * (X[n,:] @ W). 64 rows/block; thread -> 4 rows x float4.
__global__ __launch_bounds__(256) void k_gemm_scale(const float* __restrict__ X,
                                                    const float* __restrict__ W,
                                                    const float* __restrict__ dinv, int N,
                                                    float* __restrict__ G) {
    __shared__ float4 Ws[64 * 16];      // W row-major as float4
    __shared__ float Xs[64][65];
    int tid = threadIdx.x;
    const float4* W4 = (const float4*)W;
    for (int i = tid; i < 64 * 16; i += 256) Ws[i] = W4[i];
    int rowBase = blockIdx.x * 64;
    for (int i = tid; i < 1024; i += 256) {
        int r = i >> 4, f4 = i & 15;
        float4 v = make_float4(0.f, 0.f, 0.f, 0.f);
        if (rowBase + r < N) v = ((const float4*)X)[(size_t)(rowBase + r) * 16 + f4];
        Xs[r][f4 * 4 + 0] = v.x; Xs[r][f4 * 4 + 1] = v.y;
        Xs[r][f4 * 4 + 2] = v.z; Xs[r][f4 * 4 + 3] = v.w;
    }
    __syncthreads();
    int r0 = (tid >> 4) * 4;
    int c4 = tid & 15;
    float4 acc0 = make_float4(0,0,0,0), acc1 = acc0, acc2 = acc0, acc3 = acc0;
#pragma unroll
    for (int k = 0; k < 64; k++) {
        float4 w = Ws[k * 16 + c4];
        float x0 = Xs[r0 + 0][k], x1 = Xs[r0 + 1][k], x2 = Xs[r0 + 2][k], x3 = Xs[r0 + 3][k];
        acc0.x += x0 * w.x; acc0.y += x0 * w.y; acc0.z += x0 * w.z; acc0.w += x0 * w.w;
        acc1.x += x1 * w.x; acc1.y += x1 * w.y; acc1.z += x1 * w.z; acc1.w += x1 * w.w;
        acc2.x += x2 * w.x; acc2.y += x2 * w.y; acc2.z += x2 * w.z; acc2.w += x2 * w.w;
        acc3.x += x3 * w.x; acc3.y += x3 * w.y; acc3.z += x3 * w.z; acc3.w += x3 * w.w;
    }
    float4* G4 = (float4*)G;
    float4 a[4] = {acc0, acc1, acc2, acc3};
#pragma unroll
    for (int i = 0; i < 4; i++) {
        int row = rowBase + r0 + i;
        if (row < N) {
            float dn = dinv[row];
            float4 v = a[i];
            v.x *= dn; v.y *= dn; v.z *= dn; v.w *= dn;
            G4[(size_t)row * 16 + c4] = v;
        }
    }
}

// One node per wave; lane = feature (scalar f32, 256B coalesced row loads).
// Main loop: unconditional 8-wide batches (8 independent loads in flight).
// Tail (<8): masked batch. No shfl, no atomics.
__global__ __launch_bounds__(256) void k_agg(const float* __restrict__ Gm,
                                             const int* __restrict__ row_ptr,
                                             const int* __restrict__ col,
                                             const float* __restrict__ dinv,
                                             const float* __restrict__ bias, int N,
                                             float* __restrict__ Out) {
    int w = threadIdx.x >> 6;
    int c = threadIdx.x & 63;
    int n = blockIdx.x * 4 + w;
    if (n >= N) return;
    int lo = row_ptr[n], hi = row_ptr[n + 1];
    float acc = Gm[(size_t)n * FDIM + c];
    int e = lo;
    for (; e + 8 <= hi; e += 8) {
        int s0 = col[e + 0], s1 = col[e + 1], s2 = col[e + 2], s3 = col[e + 3];
        int s4 = col[e + 4], s5 = col[e + 5], s6 = col[e + 6], s7 = col[e + 7];
        float a0 = Gm[(size_t)s0 * FDIM + c];
        float a1 = Gm[(size_t)s1 * FDIM + c];
        float a2 = Gm[(size_t)s2 * FDIM + c];
        float a3 = Gm[(size_t)s3 * FDIM + c];
        float a4 = Gm[(size_t)s4 * FDIM + c];
        float a5 = Gm[(size_t)s5 * FDIM + c];
        float a6 = Gm[(size_t)s6 * FDIM + c];
        float a7 = Gm[(size_t)s7 * FDIM + c];
        acc += ((a0 + a1) + (a2 + a3)) + ((a4 + a5) + (a6 + a7));
    }
    if (e < hi) {
        int s[8]; float a[8]; int cnt = hi - e;
#pragma unroll
        for (int k = 0; k < 8; k++) s[k] = (k < cnt) ? col[e + k] : col[e];
#pragma unroll
        for (int k = 0; k < 8; k++) a[k] = Gm[(size_t)s[k] * FDIM + c];
#pragma unroll
        for (int k = 0; k < 8; k++) acc += (k < cnt) ? a[k] : 0.f;
    }
    float v = fmaxf(acc * dinv[n] + bias[c], 0.f);
    Out[(size_t)n * FDIM + c] = v;
}

// One block per graph: segment-sum rows [gstart[g], gstart[g+1]) of H (N x 64)
// into pool[g*128 + colOff .. +64). Zero atomics; streaming coalesced reads.
__global__ __launch_bounds__(256) void k_pool(const float4* __restrict__ H,
                                              const int* __restrict__ gstart,
                                              float* __restrict__ pool, int colOff) {
    int g = blockIdx.x;
    int lo = gstart[g], hi = gstart[g + 1];
    int c4 = threadIdx.x & 15;
    int rl = threadIdx.x >> 4;          // 16 parallel row streams
    float4 acc = make_float4(0.f, 0.f, 0.f, 0.f);
    for (int r = lo + rl; r < hi; r += 16) {
        float4 v = H[(size_t)r * 16 + c4];
        acc.x += v.x; acc.y += v.y; acc.z += v.z; acc.w += v.w;
    }
    __shared__ float4 sm[16][16];
    sm[rl][c4] = acc;
    __syncthreads();
    if (rl == 0) {
        float4 s = sm[0][c4];
#pragma unroll
        for (int k = 1; k < 16; k++) {
            float4 v = sm[k][c4];
            s.x += v.x; s.y += v.y; s.z += v.z; s.w += v.w;
        }
        float* dst = &pool[(size_t)g * 128 + colOff + c4 * 4];
        dst[0] = s.x; dst[1] = s.y; dst[2] = s.z; dst[3] = s.w;
    }
}

static inline size_t align256(size_t x) { return (x + 255) & ~(size_t)255; }

extern "C" void kernel_launch(void* const* d_in, const int* in_sizes, int n_in,
                              void* d_out, int out_size, void* d_ws, size_t ws_size,
                              hipStream_t stream) {
    const float* x     = (const float*)d_in[0];
    const int*   ei    = (const int*)d_in[1];
    const int*   batch = (const int*)d_in[2];
    const float* W1    = (const float*)d_in[3];
    const float* b1    = (const float*)d_in[4];
    const float* W2    = (const float*)d_in[5];
    const float* b2    = (const float*)d_in[6];

    const int N = in_sizes[0] / FDIM;
    const int E = in_sizes[1] / 2;
    const int G = 64;
    const int* src = ei;
    const int* dst = ei + E;

    char* p = (char*)d_ws;
    int* count   = (int*)p;   p += align256((size_t)N * 4);
    int* row_ptr = (int*)p;   p += align256(((size_t)N + 1) * 4);
    int* col     = (int*)p;   p += align256((size_t)E * 4);
    int* partial = (int*)p;   p += align256(1024 * 4);
    int* gstart  = (int*)p;   p += align256((size_t)(G + 1) * 4);
    float* dinv  = (float*)p; p += align256((size_t)N * 4);
    float* g     = (float*)p; p += align256((size_t)N * FDIM * 4);
    float* h1    = (float*)p; p += align256((size_t)N * FDIM * 4);

    float* out  = (float*)d_out;
    float* h2   = out;
    float* pool = out + (size_t)N * FDIM;   // [64,128], fully written by k_pool

    hipMemsetAsync(count, 0, (size_t)N * 4, stream);

    int eb = (E + 255) / 256;
    int nb = (N + 255) / 256;
    int S  = (N + SCAN_CHUNK - 1) / SCAN_CHUNK;
    int gemmB = (N + 63) / 64;
    int aggB  = (N + 3) / 4;

    k_count<<<eb, 256, 0, stream>>>(dst, E, count);
    k_dinv<<<nb, 256, 0, stream>>>(count, N, dinv);
    k_scan1<<<S, 256, 0, stream>>>(count, N, partial);
    k_scan2<<<1, 256, 0, stream>>>(partial, S);
    k_scan3<<<S, 256, 0, stream>>>(count, N, E, partial, row_ptr);
    k_scatter<<<eb, 256, 0, stream>>>(src, dst, E, row_ptr, count, col);
    k_bounds<<<nb, 256, 0, stream>>>(batch, N, G, gstart);

    // Layer 1
    k_gemm_scale<<<gemmB, 256, 0, stream>>>(x, W1, dinv, N, g);
    k_agg<<<aggB, 256, 0, stream>>>(g, row_ptr, col, dinv, b1, N, h1);
    k_pool<<<G, 256, 0, stream>>>((const float4*)h1, gstart, pool, 0);

    // Layer 2
    k_gemm_scale<<<gemmB, 256, 0, stream>>>(h1, W2, dinv, N, g);
    k_agg<<<aggB, 256, 0, stream>>>(g, row_ptr, col, dinv, b2, N, h2);
    k_pool<<<G, 256, 0, stream>>>((const float4*)h2, gstart, pool, 64);
}

// Round 5
// 377.125 us; speedup vs baseline: 3.7681x; 1.2449x over previous
//
#include <hip/hip_runtime.h>

// GCN: h1 = relu(GCNConv(x,W1,b1)); s1 = pool(h1); h2 = relu(GCNConv(h1,W2,b2)); s2 = pool(h2)
// out = [h2 (N*64) | per-graph rows [s1(64) s2(64)] (G*128)]
// batch is SORTED -> pooling is contiguous-range segment sum (no atomics).
// CSR build is bucketed (128 nodes/bucket) so all random writes stay in LDS.

#define FDIM 64
#define BSHIFT 7                 // 128 nodes per bucket
#define MAXNB 1024               // max buckets supported (N <= 131072)
#define BCAP 4096                // LDS capacity for one bucket's col region

// ---- pass 1: bucket histogram (LDS-privatized) ----
__global__ __launch_bounds__(256) void k_hist(const int* __restrict__ dst, int E, int NB,
                                              int* __restrict__ bucketCnt) {
    __shared__ int h[MAXNB];
    for (int i = threadIdx.x; i < NB; i += 256) h[i] = 0;
    __syncthreads();
    for (int e = blockIdx.x * blockDim.x + threadIdx.x; e < E; e += gridDim.x * blockDim.x)
        atomicAdd(&h[dst[e] >> BSHIFT], 1);
    __syncthreads();
    for (int i = threadIdx.x; i < NB; i += 256) {
        int c = h[i];
        if (c) atomicAdd(&bucketCnt[i], c);
    }
}

// ---- pass 2: scan bucket counts -> bucketStart[NB+1]; init bucketFill; row_ptr[N]=E ----
__global__ __launch_bounds__(1024) void k_bscan(const int* __restrict__ bucketCnt, int NB, int E,
                                                int* __restrict__ bucketStart,
                                                int* __restrict__ bucketFill,
                                                int* __restrict__ row_ptr, int N) {
    __shared__ int sm[MAXNB];
    int t = threadIdx.x;
    int v = (t < NB) ? bucketCnt[t] : 0;
    sm[t] = v;
    __syncthreads();
    for (int off = 1; off < MAXNB; off <<= 1) {
        int u = (t >= off) ? sm[t - off] : 0;
        __syncthreads();
        sm[t] += u;
        __syncthreads();
    }
    if (t < NB) {
        int ex = sm[t] - v;
        bucketStart[t] = ex;
        bucketFill[t] = ex;
    }
    if (t == 0) { bucketStart[NB] = E; row_ptr[N] = E; }
}

// ---- pass 3: scatter (src,dst) pairs into bucket-grouped ebuf ----
// 4096 edges per block; ranks assigned via LDS atomics; one global atomic
// per (block,bucket) reserves the output range -> grouped ~40B write runs.
__global__ __launch_bounds__(256) void k_bscat(const int* __restrict__ src,
                                               const int* __restrict__ dst, int E, int NB,
                                               int* __restrict__ bucketFill,
                                               int2* __restrict__ ebuf) {
    __shared__ int hist[MAXNB];
    __shared__ int base[MAXNB];
    for (int i = threadIdx.x; i < NB; i += 256) hist[i] = 0;
    __syncthreads();
    int e0 = blockIdx.x * BCAP;
    int s[16], d[16], r[16];
#pragma unroll
    for (int k = 0; k < 16; k++) {
        int e = e0 + k * 256 + threadIdx.x;
        bool valid = e < E;
        s[k] = valid ? src[e] : 0;
        d[k] = valid ? dst[e] : 0;
        r[k] = valid ? atomicAdd(&hist[d[k] >> BSHIFT], 1) : 0;
    }
    __syncthreads();
    for (int i = threadIdx.x; i < NB; i += 256) {
        int c = hist[i];
        base[i] = c ? atomicAdd(&bucketFill[i], c) : 0;
    }
    __syncthreads();
#pragma unroll
    for (int k = 0; k < 16; k++) {
        int e = e0 + k * 256 + threadIdx.x;
        if (e < E) ebuf[base[d[k] >> BSHIFT] + r[k]] = make_int2(s[k], d[k]);
    }
}

// ---- pass 4: per-bucket CSR finalize, entirely in LDS ----
// One block per bucket: per-node count, scan -> row_ptr & dinv, permute col
// region in LDS, write out coalesced.
__global__ __launch_bounds__(256) void k_bsort(const int2* __restrict__ ebuf,
                                               const int* __restrict__ bucketStart, int N,
                                               int* __restrict__ row_ptr,
                                               int* __restrict__ col,
                                               float* __restrict__ dinv) {
    __shared__ int cntL[128];
    __shared__ int scanL[128];
    __shared__ int fillL[128];
    __shared__ int colL[BCAP];
    int b = blockIdx.x;
    int n0 = b << BSHIFT;
    int nCnt = N - n0; if (nCnt > 128) nCnt = 128;
    int lo = bucketStart[b], hi = bucketStart[b + 1];
    int cnt = hi - lo;
    int t = threadIdx.x;
    if (t < 128) { cntL[t] = 0; fillL[t] = 0; }
    __syncthreads();
    for (int e = lo + t; e < hi; e += 256)
        atomicAdd(&cntL[ebuf[e].y - n0], 1);
    __syncthreads();
    if (t < 128) scanL[t] = cntL[t];
    __syncthreads();
    for (int off = 1; off < 128; off <<= 1) {
        int u = (t >= off && t < 128) ? scanL[t - off] : 0;
        __syncthreads();
        if (t < 128) scanL[t] += u;
        __syncthreads();
    }
    if (t < nCnt) {
        int ex = scanL[t] - cntL[t];
        row_ptr[n0 + t] = lo + ex;
        dinv[n0 + t] = rsqrtf((float)cntL[t] + 1.0f);
        scanL[t] = ex;          // keep exclusive prefix for placement
    }
    __syncthreads();
    if (cnt <= BCAP) {
        for (int e = lo + t; e < hi; e += 256) {
            int2 pr = ebuf[e];
            int d = pr.y - n0;
            int r = scanL[d] + atomicAdd(&fillL[d], 1);
            colL[r] = pr.x;
        }
        __syncthreads();
        for (int i = t; i < cnt; i += 256) col[lo + i] = colL[i];
    } else {                    // fallback (statistically unreachable)
        for (int e = lo + t; e < hi; e += 256) {
            int2 pr = ebuf[e];
            int d = pr.y - n0;
            int r = scanL[d] + atomicAdd(&fillL[d], 1);
            col[lo + r] = pr.x;
        }
    }
}

// Graph boundaries from sorted batch: gstart[g] = first node of graph g; gstart[G]=N.
__global__ void k_bounds(const int* __restrict__ batch, int N, int G, int* __restrict__ gstart) {
    int i = blockIdx.x * blockDim.x + threadIdx.x;
    if (i >= N) return;
    int b = batch[i];
    if (i == 0) { for (int g = 0; g <= b; g++) gstart[g] = 0; }
    else {
        int p = batch[i - 1];
        for (int g = p + 1; g <= b; g++) gstart[g] = i;
    }
    if (i == N - 1) { for (int g = b + 1; g <= G; g++) gstart[g] = N; }
}

// G[n,:] = dinv[n] * (X[n,:] @ W). 64 rows/block; thread -> 4 rows x float4.
__global__ __launch_bounds__(256) void k_gemm_scale(const float* __restrict__ X,
                                                    const float* __restrict__ W,
                                                    const float* __restrict__ dinv, int N,
                                                    float* __restrict__ G) {
    __shared__ float4 Ws[64 * 16];
    __shared__ float Xs[64][65];
    int tid = threadIdx.x;
    const float4* W4 = (const float4*)W;
    for (int i = tid; i < 64 * 16; i += 256) Ws[i] = W4[i];
    int rowBase = blockIdx.x * 64;
    for (int i = tid; i < 1024; i += 256) {
        int r = i >> 4, f4 = i & 15;
        float4 v = make_float4(0.f, 0.f, 0.f, 0.f);
        if (rowBase + r < N) v = ((const float4*)X)[(size_t)(rowBase + r) * 16 + f4];
        Xs[r][f4 * 4 + 0] = v.x; Xs[r][f4 * 4 + 1] = v.y;
        Xs[r][f4 * 4 + 2] = v.z; Xs[r][f4 * 4 + 3] = v.w;
    }
    __syncthreads();
    int r0 = (tid >> 4) * 4;
    int c4 = tid & 15;
    float4 acc0 = make_float4(0,0,0,0), acc1 = acc0, acc2 = acc0, acc3 = acc0;
#pragma unroll
    for (int k = 0; k < 64; k++) {
        float4 w = Ws[k * 16 + c4];
        float x0 = Xs[r0 + 0][k], x1 = Xs[r0 + 1][k], x2 = Xs[r0 + 2][k], x3 = Xs[r0 + 3][k];
        acc0.x += x0 * w.x; acc0.y += x0 * w.y; acc0.z += x0 * w.z; acc0.w += x0 * w.w;
        acc1.x += x1 * w.x; acc1.y += x1 * w.y; acc1.z += x1 * w.z; acc1.w += x1 * w.w;
        acc2.x += x2 * w.x; acc2.y += x2 * w.y; acc2.z += x2 * w.z; acc2.w += x2 * w.w;
        acc3.x += x3 * w.x; acc3.y += x3 * w.y; acc3.z += x3 * w.z; acc3.w += x3 * w.w;
    }
    float4* G4 = (float4*)G;
    float4 a[4] = {acc0, acc1, acc2, acc3};
#pragma unroll
    for (int i = 0; i < 4; i++) {
        int row = rowBase + r0 + i;
        if (row < N) {
            float dn = dinv[row];
            float4 v = a[i];
            v.x *= dn; v.y *= dn; v.z *= dn; v.w *= dn;
            G4[(size_t)row * 16 + c4] = v;
        }
    }
}

// One node per wave; lane = feature (scalar f32, 256B coalesced row loads).
// Main loop: unconditional 8-wide batches (8 independent loads in flight).
__global__ __launch_bounds__(256) void k_agg(const float* __restrict__ Gm,
                                             const int* __restrict__ row_ptr,
                                             const int* __restrict__ col,
                                             const float* __restrict__ dinv,
                                             const float* __restrict__ bias, int N,
                                             float* __restrict__ Out) {
    int w = threadIdx.x >> 6;
    int c = threadIdx.x & 63;
    int n = blockIdx.x * 4 + w;
    if (n >= N) return;
    int lo = row_ptr[n], hi = row_ptr[n + 1];
    float acc = Gm[(size_t)n * FDIM + c];
    int e = lo;
    for (; e + 8 <= hi; e += 8) {
        int s0 = col[e + 0], s1 = col[e + 1], s2 = col[e + 2], s3 = col[e + 3];
        int s4 = col[e + 4], s5 = col[e + 5], s6 = col[e + 6], s7 = col[e + 7];
        float a0 = Gm[(size_t)s0 * FDIM + c];
        float a1 = Gm[(size_t)s1 * FDIM + c];
        float a2 = Gm[(size_t)s2 * FDIM + c];
        float a3 = Gm[(size_t)s3 * FDIM + c];
        float a4 = Gm[(size_t)s4 * FDIM + c];
        float a5 = Gm[(size_t)s5 * FDIM + c];
        float a6 = Gm[(size_t)s6 * FDIM + c];
        float a7 = Gm[(size_t)s7 * FDIM + c];
        acc += ((a0 + a1) + (a2 + a3)) + ((a4 + a5) + (a6 + a7));
    }
    if (e < hi) {
        int s[8]; float a[8]; int cnt = hi - e;
#pragma unroll
        for (int k = 0; k < 8; k++) s[k] = (k < cnt) ? col[e + k] : col[e];
#pragma unroll
        for (int k = 0; k < 8; k++) a[k] = Gm[(size_t)s[k] * FDIM + c];
#pragma unroll
        for (int k = 0; k < 8; k++) acc += (k < cnt) ? a[k] : 0.f;
    }
    float v = fmaxf(acc * dinv[n] + bias[c], 0.f);
    Out[(size_t)n * FDIM + c] = v;
}

// One block per graph: segment-sum rows [gstart[g], gstart[g+1]) into pool row.
__global__ __launch_bounds__(256) void k_pool(const float4* __restrict__ H,
                                              const int* __restrict__ gstart,
                                              float* __restrict__ pool, int colOff) {
    int g = blockIdx.x;
    int lo = gstart[g], hi = gstart[g + 1];
    int c4 = threadIdx.x & 15;
    int rl = threadIdx.x >> 4;
    float4 acc = make_float4(0.f, 0.f, 0.f, 0.f);
    for (int r = lo + rl; r < hi; r += 16) {
        float4 v = H[(size_t)r * 16 + c4];
        acc.x += v.x; acc.y += v.y; acc.z += v.z; acc.w += v.w;
    }
    __shared__ float4 sm[16][16];
    sm[rl][c4] = acc;
    __syncthreads();
    if (rl == 0) {
        float4 s = sm[0][c4];
#pragma unroll
        for (int k = 1; k < 16; k++) {
            float4 v = sm[k][c4];
            s.x += v.x; s.y += v.y; s.z += v.z; s.w += v.w;
        }
        float* dst = &pool[(size_t)g * 128 + colOff + c4 * 4];
        dst[0] = s.x; dst[1] = s.y; dst[2] = s.z; dst[3] = s.w;
    }
}

static inline size_t align256(size_t x) { return (x + 255) & ~(size_t)255; }

extern "C" void kernel_launch(void* const* d_in, const int* in_sizes, int n_in,
                              void* d_out, int out_size, void* d_ws, size_t ws_size,
                              hipStream_t stream) {
    const float* x     = (const float*)d_in[0];
    const int*   ei    = (const int*)d_in[1];
    const int*   batch = (const int*)d_in[2];
    const float* W1    = (const float*)d_in[3];
    const float* b1    = (const float*)d_in[4];
    const float* W2    = (const float*)d_in[5];
    const float* b2    = (const float*)d_in[6];

    const int N = in_sizes[0] / FDIM;
    const int E = in_sizes[1] / 2;
    const int G = 64;
    const int NB = (N + 127) >> BSHIFT;   // buckets of 128 nodes
    const int* src = ei;
    const int* dst = ei + E;

    char* p = (char*)d_ws;
    int* row_ptr     = (int*)p; p += align256(((size_t)N + 1) * 4);
    int* col         = (int*)p; p += align256((size_t)E * 4);
    int* bucketCnt   = (int*)p; p += align256((size_t)MAXNB * 4);
    int* bucketStart = (int*)p; p += align256((size_t)(MAXNB + 1) * 4);
    int* bucketFill  = (int*)p; p += align256((size_t)MAXNB * 4);
    int* gstart      = (int*)p; p += align256((size_t)(G + 1) * 4);
    float* dinv      = (float*)p; p += align256((size_t)N * 4);
    float* g         = (float*)p; p += align256((size_t)N * FDIM * 4);
    float* h1        = (float*)p; p += align256((size_t)N * FDIM * 4);
    int2* ebuf = (int2*)g;   // aliases g: consumed by k_bsort before GEMM writes g

    float* out  = (float*)d_out;
    float* h2   = out;
    float* pool = out + (size_t)N * FDIM;   // [64,128], fully written by k_pool

    hipMemsetAsync(bucketCnt, 0, (size_t)MAXNB * 4, stream);

    int nb = (N + 255) / 256;
    int gemmB = (N + 63) / 64;
    int aggB  = (N + 3) / 4;
    int scatB = (E + BCAP - 1) / BCAP;

    k_hist<<<256, 256, 0, stream>>>(dst, E, NB, bucketCnt);
    k_bscan<<<1, 1024, 0, stream>>>(bucketCnt, NB, E, bucketStart, bucketFill, row_ptr, N);
    k_bscat<<<scatB, 256, 0, stream>>>(src, dst, E, NB, bucketFill, ebuf);
    k_bsort<<<NB, 256, 0, stream>>>(ebuf, bucketStart, N, row_ptr, col, dinv);
    k_bounds<<<nb, 256, 0, stream>>>(batch, N, G, gstart);

    // Layer 1
    k_gemm_scale<<<gemmB, 256, 0, stream>>>(x, W1, dinv, N, g);
    k_agg<<<aggB, 256, 0, stream>>>(g, row_ptr, col, dinv, b1, N, h1);
    k_pool<<<G, 256, 0, stream>>>((const float4*)h1, gstart, pool, 0);

    // Layer 2
    k_gemm_scale<<<gemmB, 256, 0, stream>>>(h1, W2, dinv, N, g);
    k_agg<<<aggB, 256, 0, stream>>>(g, row_ptr, col, dinv, b2, N, h2);
    k_pool<<<G, 256, 0, stream>>>((const float4*)h2, gstart, pool, 64);
}

// Round 6
// 323.873 us; speedup vs baseline: 4.3876x; 1.1644x over previous
//
#include <hip/hip_runtime.h>

// GCN: h1 = relu(GCNConv(x,W1,b1)); s1 = pool(h1); h2 = relu(GCNConv(h1,W2,b2)); s2 = pool(h2)
// out = [h2 (N*64) | per-graph rows [s1(64) s2(64)] (G*128)]
// batch is SORTED -> pooling is contiguous-range segment sum (no atomics).
// CSR build is bucketed (128 nodes/bucket) so all random writes stay in LDS.

#define FDIM 64
#define BSHIFT 7                 // 128 nodes per bucket
#define MAXNB 1024               // max buckets supported (N <= 131072)
#define BCAP 4096                // LDS capacity for one bucket's col region

// ---- pass 1: bucket histogram (LDS-privatized) ----
__global__ __launch_bounds__(256) void k_hist(const int* __restrict__ dst, int E, int NB,
                                              int* __restrict__ bucketCnt) {
    __shared__ int h[MAXNB];
    for (int i = threadIdx.x; i < NB; i += 256) h[i] = 0;
    __syncthreads();
    for (int e = blockIdx.x * blockDim.x + threadIdx.x; e < E; e += gridDim.x * blockDim.x)
        atomicAdd(&h[dst[e] >> BSHIFT], 1);
    __syncthreads();
    for (int i = threadIdx.x; i < NB; i += 256) {
        int c = h[i];
        if (c) atomicAdd(&bucketCnt[i], c);
    }
}

// ---- pass 2: scan bucket counts -> bucketStart[NB+1]; init bucketFill; row_ptr[N]=E ----
__global__ __launch_bounds__(1024) void k_bscan(const int* __restrict__ bucketCnt, int NB, int E,
                                                int* __restrict__ bucketStart,
                                                int* __restrict__ bucketFill,
                                                int* __restrict__ row_ptr, int N) {
    __shared__ int sm[MAXNB];
    int t = threadIdx.x;
    int v = (t < NB) ? bucketCnt[t] : 0;
    sm[t] = v;
    __syncthreads();
    for (int off = 1; off < MAXNB; off <<= 1) {
        int u = (t >= off) ? sm[t - off] : 0;
        __syncthreads();
        sm[t] += u;
        __syncthreads();
    }
    if (t < NB) {
        int ex = sm[t] - v;
        bucketStart[t] = ex;
        bucketFill[t] = ex;
    }
    if (t == 0) { bucketStart[NB] = E; row_ptr[N] = E; }
}

// ---- pass 3: scatter (src,dst) pairs into bucket-grouped ebuf ----
__global__ __launch_bounds__(256) void k_bscat(const int* __restrict__ src,
                                               const int* __restrict__ dst, int E, int NB,
                                               int* __restrict__ bucketFill,
                                               int2* __restrict__ ebuf) {
    __shared__ int hist[MAXNB];
    __shared__ int base[MAXNB];
    for (int i = threadIdx.x; i < NB; i += 256) hist[i] = 0;
    __syncthreads();
    int e0 = blockIdx.x * BCAP;
    int s[16], d[16], r[16];
#pragma unroll
    for (int k = 0; k < 16; k++) {
        int e = e0 + k * 256 + threadIdx.x;
        bool valid = e < E;
        s[k] = valid ? src[e] : 0;
        d[k] = valid ? dst[e] : 0;
        r[k] = valid ? atomicAdd(&hist[d[k] >> BSHIFT], 1) : 0;
    }
    __syncthreads();
    for (int i = threadIdx.x; i < NB; i += 256) {
        int c = hist[i];
        base[i] = c ? atomicAdd(&bucketFill[i], c) : 0;
    }
    __syncthreads();
#pragma unroll
    for (int k = 0; k < 16; k++) {
        int e = e0 + k * 256 + threadIdx.x;
        if (e < E) ebuf[base[d[k] >> BSHIFT] + r[k]] = make_int2(s[k], d[k]);
    }
}

// ---- pass 4: per-bucket CSR finalize, entirely in LDS ----
__global__ __launch_bounds__(256) void k_bsort(const int2* __restrict__ ebuf,
                                               const int* __restrict__ bucketStart, int N,
                                               int* __restrict__ row_ptr,
                                               int* __restrict__ col,
                                               float* __restrict__ dinv) {
    __shared__ int cntL[128];
    __shared__ int scanL[128];
    __shared__ int fillL[128];
    __shared__ int colL[BCAP];
    int b = blockIdx.x;
    int n0 = b << BSHIFT;
    int nCnt = N - n0; if (nCnt > 128) nCnt = 128;
    int lo = bucketStart[b], hi = bucketStart[b + 1];
    int cnt = hi - lo;
    int t = threadIdx.x;
    if (t < 128) { cntL[t] = 0; fillL[t] = 0; }
    __syncthreads();
    for (int e = lo + t; e < hi; e += 256)
        atomicAdd(&cntL[ebuf[e].y - n0], 1);
    __syncthreads();
    if (t < 128) scanL[t] = cntL[t];
    __syncthreads();
    for (int off = 1; off < 128; off <<= 1) {
        int u = (t >= off && t < 128) ? scanL[t - off] : 0;
        __syncthreads();
        if (t < 128) scanL[t] += u;
        __syncthreads();
    }
    if (t < nCnt) {
        int ex = scanL[t] - cntL[t];
        row_ptr[n0 + t] = lo + ex;
        dinv[n0 + t] = rsqrtf((float)cntL[t] + 1.0f);
        scanL[t] = ex;          // keep exclusive prefix for placement
    }
    __syncthreads();
    if (cnt <= BCAP) {
        for (int e = lo + t; e < hi; e += 256) {
            int2 pr = ebuf[e];
            int d = pr.y - n0;
            int r = scanL[d] + atomicAdd(&fillL[d], 1);
            colL[r] = pr.x;
        }
        __syncthreads();
        for (int i = t; i < cnt; i += 256) col[lo + i] = colL[i];
    } else {                    // fallback (statistically unreachable)
        for (int e = lo + t; e < hi; e += 256) {
            int2 pr = ebuf[e];
            int d = pr.y - n0;
            int r = scanL[d] + atomicAdd(&fillL[d], 1);
            col[lo + r] = pr.x;
        }
    }
}

// Graph boundaries from sorted batch: gstart[g] = first node of graph g; gstart[G]=N.
__global__ void k_bounds(const int* __restrict__ batch, int N, int G, int* __restrict__ gstart) {
    int i = blockIdx.x * blockDim.x + threadIdx.x;
    if (i >= N) return;
    int b = batch[i];
    if (i == 0) { for (int g = 0; g <= b; g++) gstart[g] = 0; }
    else {
        int p = batch[i - 1];
        for (int g = p + 1; g <= b; g++) gstart[g] = i;
    }
    if (i == N - 1) { for (int g = b + 1; g <= G; g++) gstart[g] = N; }
}

// G[n,:] = dinv[n] * (X[n,:] @ W). 64 rows/block; thread -> 4 rows x float4.
// launch_bounds(256,4): cap VGPR at 128 so occupancy = 4 waves/SIMD (round-5
// counter evidence: unbounded build hit 236 VGPR -> 9% occupancy, 55us).
// Xs stride 68: rows 16B-aligned (float4 staging) AND 4-row reads land on
// distinct banks (k + {0,4,8,12}).
__global__ __launch_bounds__(256, 4) void k_gemm_scale(const float* __restrict__ X,
                                                       const float* __restrict__ W,
                                                       const float* __restrict__ dinv, int N,
                                                       float* __restrict__ G) {
    __shared__ float4 Ws[64 * 16];
    __shared__ float Xs[64][68];
    int tid = threadIdx.x;
    const float4* W4 = (const float4*)W;
    for (int i = tid; i < 64 * 16; i += 256) Ws[i] = W4[i];
    int rowBase = blockIdx.x * 64;
    for (int i = tid; i < 1024; i += 256) {
        int r = i >> 4, f4 = i & 15;
        float4 v = make_float4(0.f, 0.f, 0.f, 0.f);
        if (rowBase + r < N) v = ((const float4*)X)[(size_t)(rowBase + r) * 16 + f4];
        *(float4*)&Xs[r][f4 * 4] = v;
    }
    __syncthreads();
    int r0 = (tid >> 4) * 4;
    int c4 = tid & 15;
    float4 acc0 = make_float4(0,0,0,0), acc1 = acc0, acc2 = acc0, acc3 = acc0;
#pragma unroll 16
    for (int k = 0; k < 64; k++) {
        float4 w = Ws[k * 16 + c4];
        float x0 = Xs[r0 + 0][k], x1 = Xs[r0 + 1][k], x2 = Xs[r0 + 2][k], x3 = Xs[r0 + 3][k];
        acc0.x += x0 * w.x; acc0.y += x0 * w.y; acc0.z += x0 * w.z; acc0.w += x0 * w.w;
        acc1.x += x1 * w.x; acc1.y += x1 * w.y; acc1.z += x1 * w.z; acc1.w += x1 * w.w;
        acc2.x += x2 * w.x; acc2.y += x2 * w.y; acc2.z += x2 * w.z; acc2.w += x2 * w.w;
        acc3.x += x3 * w.x; acc3.y += x3 * w.y; acc3.z += x3 * w.z; acc3.w += x3 * w.w;
    }
    float4* G4 = (float4*)G;
    float4 a[4] = {acc0, acc1, acc2, acc3};
#pragma unroll
    for (int i = 0; i < 4; i++) {
        int row = rowBase + r0 + i;
        if (row < N) {
            float dn = dinv[row];
            float4 v = a[i];
            v.x *= dn; v.y *= dn; v.z *= dn; v.w *= dn;
            G4[(size_t)row * 16 + c4] = v;
        }
    }
}

// One node per wave; lane = feature (scalar f32, 256B coalesced row loads).
// Main loop: unconditional 8-wide batches (8 independent loads in flight).
__global__ __launch_bounds__(256) void k_agg(const float* __restrict__ Gm,
                                             const int* __restrict__ row_ptr,
                                             const int* __restrict__ col,
                                             const float* __restrict__ dinv,
                                             const float* __restrict__ bias, int N,
                                             float* __restrict__ Out) {
    int w = threadIdx.x >> 6;
    int c = threadIdx.x & 63;
    int n = blockIdx.x * 4 + w;
    if (n >= N) return;
    int lo = row_ptr[n], hi = row_ptr[n + 1];
    float acc = Gm[(size_t)n * FDIM + c];
    int e = lo;
    for (; e + 8 <= hi; e += 8) {
        int s0 = col[e + 0], s1 = col[e + 1], s2 = col[e + 2], s3 = col[e + 3];
        int s4 = col[e + 4], s5 = col[e + 5], s6 = col[e + 6], s7 = col[e + 7];
        float a0 = Gm[(size_t)s0 * FDIM + c];
        float a1 = Gm[(size_t)s1 * FDIM + c];
        float a2 = Gm[(size_t)s2 * FDIM + c];
        float a3 = Gm[(size_t)s3 * FDIM + c];
        float a4 = Gm[(size_t)s4 * FDIM + c];
        float a5 = Gm[(size_t)s5 * FDIM + c];
        float a6 = Gm[(size_t)s6 * FDIM + c];
        float a7 = Gm[(size_t)s7 * FDIM + c];
        acc += ((a0 + a1) + (a2 + a3)) + ((a4 + a5) + (a6 + a7));
    }
    if (e < hi) {
        int s[8]; float a[8]; int cnt = hi - e;
#pragma unroll
        for (int k = 0; k < 8; k++) s[k] = (k < cnt) ? col[e + k] : col[e];
#pragma unroll
        for (int k = 0; k < 8; k++) a[k] = Gm[(size_t)s[k] * FDIM + c];
#pragma unroll
        for (int k = 0; k < 8; k++) acc += (k < cnt) ? a[k] : 0.f;
    }
    float v = fmaxf(acc * dinv[n] + bias[c], 0.f);
    Out[(size_t)n * FDIM + c] = v;
}

// One block per graph: segment-sum rows [gstart[g], gstart[g+1]) into pool row.
__global__ __launch_bounds__(256) void k_pool(const float4* __restrict__ H,
                                              const int* __restrict__ gstart,
                                              float* __restrict__ pool, int colOff) {
    int g = blockIdx.x;
    int lo = gstart[g], hi = gstart[g + 1];
    int c4 = threadIdx.x & 15;
    int rl = threadIdx.x >> 4;
    float4 acc = make_float4(0.f, 0.f, 0.f, 0.f);
    for (int r = lo + rl; r < hi; r += 16) {
        float4 v = H[(size_t)r * 16 + c4];
        acc.x += v.x; acc.y += v.y; acc.z += v.z; acc.w += v.w;
    }
    __shared__ float4 sm[16][16];
    sm[rl][c4] = acc;
    __syncthreads();
    if (rl == 0) {
        float4 s = sm[0][c4];
#pragma unroll
        for (int k = 1; k < 16; k++) {
            float4 v = sm[k][c4];
            s.x += v.x; s.y += v.y; s.z += v.z; s.w += v.w;
        }
        float* dst = &pool[(size_t)g * 128 + colOff + c4 * 4];
        dst[0] = s.x; dst[1] = s.y; dst[2] = s.z; dst[3] = s.w;
    }
}

static inline size_t align256(size_t x) { return (x + 255) & ~(size_t)255; }

extern "C" void kernel_launch(void* const* d_in, const int* in_sizes, int n_in,
                              void* d_out, int out_size, void* d_ws, size_t ws_size,
                              hipStream_t stream) {
    const float* x     = (const float*)d_in[0];
    const int*   ei    = (const int*)d_in[1];
    const int*   batch = (const int*)d_in[2];
    const float* W1    = (const float*)d_in[3];
    const float* b1    = (const float*)d_in[4];
    const float* W2    = (const float*)d_in[5];
    const float* b2    = (const float*)d_in[6];

    const int N = in_sizes[0] / FDIM;
    const int E = in_sizes[1] / 2;
    const int G = 64;
    const int NB = (N + 127) >> BSHIFT;   // buckets of 128 nodes
    const int* src = ei;
    const int* dst = ei + E;

    char* p = (char*)d_ws;
    int* row_ptr     = (int*)p; p += align256(((size_t)N + 1) * 4);
    int* col         = (int*)p; p += align256((size_t)E * 4);
    int* bucketCnt   = (int*)p; p += align256((size_t)MAXNB * 4);
    int* bucketStart = (int*)p; p += align256((size_t)(MAXNB + 1) * 4);
    int* bucketFill  = (int*)p; p += align256((size_t)MAXNB * 4);
    int* gstart      = (int*)p; p += align256((size_t)(G + 1) * 4);
    float* dinv      = (float*)p; p += align256((size_t)N * 4);
    float* g         = (float*)p; p += align256((size_t)N * FDIM * 4);
    float* h1        = (float*)p; p += align256((size_t)N * FDIM * 4);
    int2* ebuf = (int2*)g;   // aliases g: consumed by k_bsort before GEMM writes g

    float* out  = (float*)d_out;
    float* h2   = out;
    float* pool = out + (size_t)N * FDIM;   // [64,128], fully written by k_pool

    hipMemsetAsync(bucketCnt, 0, (size_t)MAXNB * 4, stream);

    int nb = (N + 255) / 256;
    int gemmB = (N + 63) / 64;
    int aggB  = (N + 3) / 4;
    int scatB = (E + BCAP - 1) / BCAP;

    k_hist<<<256, 256, 0, stream>>>(dst, E, NB, bucketCnt);
    k_bscan<<<1, 1024, 0, stream>>>(bucketCnt, NB, E, bucketStart, bucketFill, row_ptr, N);
    k_bscat<<<scatB, 256, 0, stream>>>(src, dst, E, NB, bucketFill, ebuf);
    k_bsort<<<NB, 256, 0, stream>>>(ebuf, bucketStart, N, row_ptr, col, dinv);
    k_bounds<<<nb, 256, 0, stream>>>(batch, N, G, gstart);

    // Layer 1
    k_gemm_scale<<<gemmB, 256, 0, stream>>>(x, W1, dinv, N, g);
    k_agg<<<aggB, 256, 0, stream>>>(g, row_ptr, col, dinv, b1, N, h1);
    k_pool<<<G, 256, 0, stream>>>((const float4*)h1, gstart, pool, 0);

    // Layer 2
    k_gemm_scale<<<gemmB, 256, 0, stream>>>(h1, W2, dinv, N, g);
    k_agg<<<aggB, 256, 0, stream>>>(g, row_ptr, col, dinv, b2, N, h2);
    k_pool<<<G, 256, 0, stream>>>((const float4*)h2, gstart, pool, 64);
}

// Round 7
// 300.960 us; speedup vs baseline: 4.7217x; 1.0761x over previous
//
#include <hip/hip_runtime.h>

// GCN: h1 = relu(GCNConv(x,W1,b1)); s1 = pool(h1); h2 = relu(GCNConv(h1,W2,b2)); s2 = pool(h2)
// out = [h2 (N*64) | per-graph rows [s1(64) s2(64)] (G*128)]
// batch is SORTED -> pooling is contiguous-range segment sum (no atomics).
// CSR build is bucketed (128 nodes/bucket) so all random writes stay in LDS.
// Gather buffer g is stored bf16 (round-6 evidence: k_agg FETCH=147MB on a
// 25.6MB fp32 working set -> L2-capacity re-fetch; halving rows to 128B
// halves miss bytes and doubles residency). Accumulation stays fp32.

#define FDIM 64
#define BSHIFT 7                 // 128 nodes per bucket
#define MAXNB 1024               // max buckets supported (N <= 131072)
#define BCAP 4096                // LDS capacity for one bucket's col region

__device__ __forceinline__ unsigned short f2bf(float f) {   // RNE
    union { float f; unsigned int u; } a; a.f = f;
    unsigned int u = a.u;
    unsigned int r = u + 0x7fffu + ((u >> 16) & 1u);
    return (unsigned short)(r >> 16);
}
__device__ __forceinline__ float bf2f(unsigned short s) {
    union { unsigned int u; float f; } a; a.u = ((unsigned int)s) << 16;
    return a.f;
}

// ---- pass 1: bucket histogram (LDS-privatized) ----
__global__ __launch_bounds__(256) void k_hist(const int* __restrict__ dst, int E, int NB,
                                              int* __restrict__ bucketCnt) {
    __shared__ int h[MAXNB];
    for (int i = threadIdx.x; i < NB; i += 256) h[i] = 0;
    __syncthreads();
    for (int e = blockIdx.x * blockDim.x + threadIdx.x; e < E; e += gridDim.x * blockDim.x)
        atomicAdd(&h[dst[e] >> BSHIFT], 1);
    __syncthreads();
    for (int i = threadIdx.x; i < NB; i += 256) {
        int c = h[i];
        if (c) atomicAdd(&bucketCnt[i], c);
    }
}

// ---- pass 2: scan bucket counts -> bucketStart[NB+1]; init bucketFill; row_ptr[N]=E ----
__global__ __launch_bounds__(1024) void k_bscan(const int* __restrict__ bucketCnt, int NB, int E,
                                                int* __restrict__ bucketStart,
                                                int* __restrict__ bucketFill,
                                                int* __restrict__ row_ptr, int N) {
    __shared__ int sm[MAXNB];
    int t = threadIdx.x;
    int v = (t < NB) ? bucketCnt[t] : 0;
    sm[t] = v;
    __syncthreads();
    for (int off = 1; off < MAXNB; off <<= 1) {
        int u = (t >= off) ? sm[t - off] : 0;
        __syncthreads();
        sm[t] += u;
        __syncthreads();
    }
    if (t < NB) {
        int ex = sm[t] - v;
        bucketStart[t] = ex;
        bucketFill[t] = ex;
    }
    if (t == 0) { bucketStart[NB] = E; row_ptr[N] = E; }
}

// ---- pass 3: scatter (src,dst) pairs into bucket-grouped ebuf ----
__global__ __launch_bounds__(256) void k_bscat(const int* __restrict__ src,
                                               const int* __restrict__ dst, int E, int NB,
                                               int* __restrict__ bucketFill,
                                               int2* __restrict__ ebuf) {
    __shared__ int hist[MAXNB];
    __shared__ int base[MAXNB];
    for (int i = threadIdx.x; i < NB; i += 256) hist[i] = 0;
    __syncthreads();
    int e0 = blockIdx.x * BCAP;
    int s[16], d[16], r[16];
#pragma unroll
    for (int k = 0; k < 16; k++) {
        int e = e0 + k * 256 + threadIdx.x;
        bool valid = e < E;
        s[k] = valid ? src[e] : 0;
        d[k] = valid ? dst[e] : 0;
        r[k] = valid ? atomicAdd(&hist[d[k] >> BSHIFT], 1) : 0;
    }
    __syncthreads();
    for (int i = threadIdx.x; i < NB; i += 256) {
        int c = hist[i];
        base[i] = c ? atomicAdd(&bucketFill[i], c) : 0;
    }
    __syncthreads();
#pragma unroll
    for (int k = 0; k < 16; k++) {
        int e = e0 + k * 256 + threadIdx.x;
        if (e < E) ebuf[base[d[k] >> BSHIFT] + r[k]] = make_int2(s[k], d[k]);
    }
}

// ---- pass 4: per-bucket CSR finalize, entirely in LDS ----
__global__ __launch_bounds__(256) void k_bsort(const int2* __restrict__ ebuf,
                                               const int* __restrict__ bucketStart, int N,
                                               int* __restrict__ row_ptr,
                                               int* __restrict__ col,
                                               float* __restrict__ dinv) {
    __shared__ int cntL[128];
    __shared__ int scanL[128];
    __shared__ int fillL[128];
    __shared__ int colL[BCAP];
    int b = blockIdx.x;
    int n0 = b << BSHIFT;
    int nCnt = N - n0; if (nCnt > 128) nCnt = 128;
    int lo = bucketStart[b], hi = bucketStart[b + 1];
    int cnt = hi - lo;
    int t = threadIdx.x;
    if (t < 128) { cntL[t] = 0; fillL[t] = 0; }
    __syncthreads();
    for (int e = lo + t; e < hi; e += 256)
        atomicAdd(&cntL[ebuf[e].y - n0], 1);
    __syncthreads();
    if (t < 128) scanL[t] = cntL[t];
    __syncthreads();
    for (int off = 1; off < 128; off <<= 1) {
        int u = (t >= off && t < 128) ? scanL[t - off] : 0;
        __syncthreads();
        if (t < 128) scanL[t] += u;
        __syncthreads();
    }
    if (t < nCnt) {
        int ex = scanL[t] - cntL[t];
        row_ptr[n0 + t] = lo + ex;
        dinv[n0 + t] = rsqrtf((float)cntL[t] + 1.0f);
        scanL[t] = ex;          // keep exclusive prefix for placement
    }
    __syncthreads();
    if (cnt <= BCAP) {
        for (int e = lo + t; e < hi; e += 256) {
            int2 pr = ebuf[e];
            int d = pr.y - n0;
            int r = scanL[d] + atomicAdd(&fillL[d], 1);
            colL[r] = pr.x;
        }
        __syncthreads();
        for (int i = t; i < cnt; i += 256) col[lo + i] = colL[i];
    } else {                    // fallback (statistically unreachable)
        for (int e = lo + t; e < hi; e += 256) {
            int2 pr = ebuf[e];
            int d = pr.y - n0;
            int r = scanL[d] + atomicAdd(&fillL[d], 1);
            col[lo + r] = pr.x;
        }
    }
}

// Graph boundaries from sorted batch: gstart[g] = first node of graph g; gstart[G]=N.
__global__ void k_bounds(const int* __restrict__ batch, int N, int G, int* __restrict__ gstart) {
    int i = blockIdx.x * blockDim.x + threadIdx.x;
    if (i >= N) return;
    int b = batch[i];
    if (i == 0) { for (int g = 0; g <= b; g++) gstart[g] = 0; }
    else {
        int p = batch[i - 1];
        for (int g = p + 1; g <= b; g++) gstart[g] = i;
    }
    if (i == N - 1) { for (int g = b + 1; g <= G; g++) gstart[g] = N; }
}

// Gb[n,:] = bf16( dinv[n] * (X[n,:] @ W) ). 64 rows/block; thread -> 4 rows x 4 cols.
// launch_bounds(256,4): cap VGPR at 128 (round-5: unbounded hit 236 VGPR -> 9% occ).
__global__ __launch_bounds__(256, 4) void k_gemm_scale(const float* __restrict__ X,
                                                       const float* __restrict__ W,
                                                       const float* __restrict__ dinv, int N,
                                                       unsigned short* __restrict__ Gb) {
    __shared__ float4 Ws[64 * 16];
    __shared__ float Xs[64][68];
    int tid = threadIdx.x;
    const float4* W4 = (const float4*)W;
    for (int i = tid; i < 64 * 16; i += 256) Ws[i] = W4[i];
    int rowBase = blockIdx.x * 64;
    for (int i = tid; i < 1024; i += 256) {
        int r = i >> 4, f4 = i & 15;
        float4 v = make_float4(0.f, 0.f, 0.f, 0.f);
        if (rowBase + r < N) v = ((const float4*)X)[(size_t)(rowBase + r) * 16 + f4];
        *(float4*)&Xs[r][f4 * 4] = v;
    }
    __syncthreads();
    int r0 = (tid >> 4) * 4;
    int c4 = tid & 15;
    float4 acc0 = make_float4(0,0,0,0), acc1 = acc0, acc2 = acc0, acc3 = acc0;
#pragma unroll 16
    for (int k = 0; k < 64; k++) {
        float4 w = Ws[k * 16 + c4];
        float x0 = Xs[r0 + 0][k], x1 = Xs[r0 + 1][k], x2 = Xs[r0 + 2][k], x3 = Xs[r0 + 3][k];
        acc0.x += x0 * w.x; acc0.y += x0 * w.y; acc0.z += x0 * w.z; acc0.w += x0 * w.w;
        acc1.x += x1 * w.x; acc1.y += x1 * w.y; acc1.z += x1 * w.z; acc1.w += x1 * w.w;
        acc2.x += x2 * w.x; acc2.y += x2 * w.y; acc2.z += x2 * w.z; acc2.w += x2 * w.w;
        acc3.x += x3 * w.x; acc3.y += x3 * w.y; acc3.z += x3 * w.z; acc3.w += x3 * w.w;
    }
    float4 a[4] = {acc0, acc1, acc2, acc3};
    ushort4* GB4 = (ushort4*)Gb;
#pragma unroll
    for (int i = 0; i < 4; i++) {
        int row = rowBase + r0 + i;
        if (row < N) {
            float dn = dinv[row];
            ushort4 pk;
            pk.x = f2bf(a[i].x * dn);
            pk.y = f2bf(a[i].y * dn);
            pk.z = f2bf(a[i].z * dn);
            pk.w = f2bf(a[i].w * dn);
            GB4[(size_t)row * 16 + c4] = pk;   // 8B/lane, 128B/row
        }
    }
}

// One node per wave; lane = feature. Gather rows are bf16 (128B, coalesced
// ushort/lane); accumulate fp32. 8 independent gathers in flight.
__global__ __launch_bounds__(256) void k_agg(const unsigned short* __restrict__ Gb,
                                             const int* __restrict__ row_ptr,
                                             const int* __restrict__ col,
                                             const float* __restrict__ dinv,
                                             const float* __restrict__ bias, int N,
                                             float* __restrict__ Out) {
    int w = threadIdx.x >> 6;
    int c = threadIdx.x & 63;
    int n = blockIdx.x * 4 + w;
    if (n >= N) return;
    int lo = row_ptr[n], hi = row_ptr[n + 1];
    float acc = bf2f(Gb[(size_t)n * FDIM + c]);
    int e = lo;
    for (; e + 8 <= hi; e += 8) {
        int s0 = col[e + 0], s1 = col[e + 1], s2 = col[e + 2], s3 = col[e + 3];
        int s4 = col[e + 4], s5 = col[e + 5], s6 = col[e + 6], s7 = col[e + 7];
        unsigned short u0 = Gb[(size_t)s0 * FDIM + c];
        unsigned short u1 = Gb[(size_t)s1 * FDIM + c];
        unsigned short u2 = Gb[(size_t)s2 * FDIM + c];
        unsigned short u3 = Gb[(size_t)s3 * FDIM + c];
        unsigned short u4 = Gb[(size_t)s4 * FDIM + c];
        unsigned short u5 = Gb[(size_t)s5 * FDIM + c];
        unsigned short u6 = Gb[(size_t)s6 * FDIM + c];
        unsigned short u7 = Gb[(size_t)s7 * FDIM + c];
        acc += ((bf2f(u0) + bf2f(u1)) + (bf2f(u2) + bf2f(u3)))
             + ((bf2f(u4) + bf2f(u5)) + (bf2f(u6) + bf2f(u7)));
    }
    if (e < hi) {
        int s[8]; unsigned short u[8]; int cnt = hi - e;
#pragma unroll
        for (int k = 0; k < 8; k++) s[k] = (k < cnt) ? col[e + k] : col[e];
#pragma unroll
        for (int k = 0; k < 8; k++) u[k] = Gb[(size_t)s[k] * FDIM + c];
#pragma unroll
        for (int k = 0; k < 8; k++) acc += (k < cnt) ? bf2f(u[k]) : 0.f;
    }
    float v = fmaxf(acc * dinv[n] + bias[c], 0.f);
    Out[(size_t)n * FDIM + c] = v;
}

// One block per graph: segment-sum rows [gstart[g], gstart[g+1]) into pool row.
__global__ __launch_bounds__(256) void k_pool(const float4* __restrict__ H,
                                              const int* __restrict__ gstart,
                                              float* __restrict__ pool, int colOff) {
    int g = blockIdx.x;
    int lo = gstart[g], hi = gstart[g + 1];
    int c4 = threadIdx.x & 15;
    int rl = threadIdx.x >> 4;
    float4 acc = make_float4(0.f, 0.f, 0.f, 0.f);
    for (int r = lo + rl; r < hi; r += 16) {
        float4 v = H[(size_t)r * 16 + c4];
        acc.x += v.x; acc.y += v.y; acc.z += v.z; acc.w += v.w;
    }
    __shared__ float4 sm[16][16];
    sm[rl][c4] = acc;
    __syncthreads();
    if (rl == 0) {
        float4 s = sm[0][c4];
#pragma unroll
        for (int k = 1; k < 16; k++) {
            float4 v = sm[k][c4];
            s.x += v.x; s.y += v.y; s.z += v.z; s.w += v.w;
        }
        float* dst = &pool[(size_t)g * 128 + colOff + c4 * 4];
        dst[0] = s.x; dst[1] = s.y; dst[2] = s.z; dst[3] = s.w;
    }
}

static inline size_t align256(size_t x) { return (x + 255) & ~(size_t)255; }

extern "C" void kernel_launch(void* const* d_in, const int* in_sizes, int n_in,
                              void* d_out, int out_size, void* d_ws, size_t ws_size,
                              hipStream_t stream) {
    const float* x     = (const float*)d_in[0];
    const int*   ei    = (const int*)d_in[1];
    const int*   batch = (const int*)d_in[2];
    const float* W1    = (const float*)d_in[3];
    const float* b1    = (const float*)d_in[4];
    const float* W2    = (const float*)d_in[5];
    const float* b2    = (const float*)d_in[6];

    const int N = in_sizes[0] / FDIM;
    const int E = in_sizes[1] / 2;
    const int G = 64;
    const int NB = (N + 127) >> BSHIFT;   // buckets of 128 nodes
    const int* src = ei;
    const int* dst = ei + E;

    char* p = (char*)d_ws;
    int* row_ptr     = (int*)p; p += align256(((size_t)N + 1) * 4);
    int* col         = (int*)p; p += align256((size_t)E * 4);
    int* bucketCnt   = (int*)p; p += align256((size_t)MAXNB * 4);
    int* bucketStart = (int*)p; p += align256((size_t)(MAXNB + 1) * 4);
    int* bucketFill  = (int*)p; p += align256((size_t)MAXNB * 4);
    int* gstart      = (int*)p; p += align256((size_t)(G + 1) * 4);
    float* dinv      = (float*)p; p += align256((size_t)N * 4);
    float* g         = (float*)p; p += align256((size_t)N * FDIM * 4);  // holds ebuf then bf16 g
    float* h1        = (float*)p; p += align256((size_t)N * FDIM * 4);
    int2* ebuf = (int2*)g;                  // 9.6MB, consumed by k_bsort before GEMM writes g
    unsigned short* gb = (unsigned short*)g; // bf16 gather buffer, 12.8MB

    float* out  = (float*)d_out;
    float* h2   = out;
    float* pool = out + (size_t)N * FDIM;   // [64,128], fully written by k_pool

    hipMemsetAsync(bucketCnt, 0, (size_t)MAXNB * 4, stream);

    int nb = (N + 255) / 256;
    int gemmB = (N + 63) / 64;
    int aggB  = (N + 3) / 4;
    int scatB = (E + BCAP - 1) / BCAP;

    k_hist<<<256, 256, 0, stream>>>(dst, E, NB, bucketCnt);
    k_bscan<<<1, 1024, 0, stream>>>(bucketCnt, NB, E, bucketStart, bucketFill, row_ptr, N);
    k_bscat<<<scatB, 256, 0, stream>>>(src, dst, E, NB, bucketFill, ebuf);
    k_bsort<<<NB, 256, 0, stream>>>(ebuf, bucketStart, N, row_ptr, col, dinv);
    k_bounds<<<nb, 256, 0, stream>>>(batch, N, G, gstart);

    // Layer 1
    k_gemm_scale<<<gemmB, 256, 0, stream>>>(x, W1, dinv, N, gb);
    k_agg<<<aggB, 256, 0, stream>>>(gb, row_ptr, col, dinv, b1, N, h1);
    k_pool<<<G, 256, 0, stream>>>((const float4*)h1, gstart, pool, 0);

    // Layer 2
    k_gemm_scale<<<gemmB, 256, 0, stream>>>(h1, W2, dinv, N, gb);
    k_agg<<<aggB, 256, 0, stream>>>(gb, row_ptr, col, dinv, b2, N, h2);
    k_pool<<<G, 256, 0, stream>>>((const float4*)h2, gstart, pool, 64);
}